// Round 15
// baseline (120.177 us; speedup 1.0000x reference)
//
#include <hip/hip_runtime.h>
#include <hip/hip_bf16.h>
#include <stdint.h>

#define B_ 8
#define S_ 1024
#define NH_ 16
#define D_ 64
#define H_ 1024
#define M_TOT (B_*S_)
#define LOG2E 1.44269504088896f

typedef __attribute__((ext_vector_type(8))) short short8;
typedef __attribute__((ext_vector_type(4))) float f32x4;
typedef __attribute__((ext_vector_type(16))) float f32x16;

#if __has_builtin(__builtin_amdgcn_exp2f)
#define EXP2(x) __builtin_amdgcn_exp2f(x)
#else
#define EXP2(x) __expf((x) * 0.69314718056f)
#endif

static __device__ __forceinline__ unsigned short f2bf(float f) {
  union { float f; unsigned u; } c; c.f = f;
  unsigned u = c.u;
  return (unsigned short)((u + 0x7fffu + ((u >> 16) & 1u)) >> 16);
}

static __device__ __forceinline__ void gld_lds16(void* lds, const void* g) {
  __builtin_amdgcn_global_load_lds((const __attribute__((address_space(1))) unsigned*)g,
                                   (__attribute__((address_space(3))) unsigned*)lds, 16, 0, 0);
}

#define WAIT_LGKM0() asm volatile("s_waitcnt lgkmcnt(0)" ::: "memory")
#define WAIT_VM(n)   asm volatile("s_waitcnt vmcnt(" #n ")" ::: "memory")
#define SBAR()       __builtin_amdgcn_s_barrier()
#define SCHED0()     __builtin_amdgcn_sched_barrier(0)
#define PRIO1()      __builtin_amdgcn_s_setprio(1)
#define PRIO0()      __builtin_amdgcn_s_setprio(0)

// ---------------- kernel 1: f32 -> bf16 conversion (X and the 3 weights) ----
__global__ void cvt_f32_bf16(const float* __restrict__ X,
                             const float* __restrict__ Wq,
                             const float* __restrict__ Wk,
                             const float* __restrict__ Wv,
                             unsigned short* __restrict__ Xbf,
                             unsigned short* __restrict__ Wbf) {
  const long long NX = (long long)M_TOT * H_;
  const long long NW = (long long)H_ * H_;
  long long t = (long long)blockIdx.x * blockDim.x + threadIdx.x;
  const long long stride = (long long)gridDim.x * blockDim.x;
  const long long total4 = (NX + 3 * NW) >> 2;
  for (; t < total4; t += stride) {
    long long e = t << 2;
    const float* src; unsigned short* dst;
    if (e < NX) { src = X + e; dst = Xbf + e; }
    else {
      long long r = e - NX;
      int w = (int)(r / NW);
      long long o = r - (long long)w * NW;
      src = (w == 0 ? Wq : (w == 1 ? Wk : Wv)) + o;
      dst = Wbf + (long long)w * NW + o;
    }
    float4 v = *(const float4*)src;
    ushort4 u;
    u.x = f2bf(v.x); u.y = f2bf(v.y); u.z = f2bf(v.z); u.w = f2bf(v.w);
    *(ushort4*)dst = u;
  }
}

// ---------------- shared GEMM macros (R9-verified) --------------------------
#define QBM 256
#define QBN 256
#define QBK 64
#define REG_B 32768
#define BUFSZ 65536
#define VBUF  49152

#define MMQ(I0, J0, AF, BF)                                               \
  _Pragma("unroll")                                                       \
  for (int a_ = 0; a_ < 4; ++a_)                                          \
    _Pragma("unroll")                                                     \
    for (int b_ = 0; b_ < 2; ++b_)                                        \
      _Pragma("unroll")                                                   \
      for (int k_ = 0; k_ < 2; ++k_)                                      \
        acc[(I0) + a_][(J0) + b_] = __builtin_amdgcn_mfma_f32_16x16x32_bf16( \
            AF[a_][k_], BF[b_][k_], acc[(I0) + a_][(J0) + b_], 0, 0, 0);

#define RD_A(BUF, MS)                                                     \
  _Pragma("unroll")                                                       \
  for (int f_ = 0; f_ < 4; ++f_)                                          \
    _Pragma("unroll")                                                     \
    for (int k_ = 0; k_ < 2; ++k_) A[f_][k_] = rdA(BUF, MS, f_, k_);

#define RD_B(DST, BUF, NS)                                                \
  _Pragma("unroll")                                                       \
  for (int f_ = 0; f_ < 2; ++f_)                                          \
    _Pragma("unroll")                                                     \
    for (int k_ = 0; k_ < 2; ++k_) DST[f_][k_] = rdB(BUF, NS, f_, k_);

// ---------------- kernel 2a: Q+K GEMM (R13 verbatim) -----------------------
__global__ __launch_bounds__(512, 1) void qkv_gemm_qk(
    const unsigned short* __restrict__ Xbf,
    const unsigned short* __restrict__ Wbf,
    const float* __restrict__ bq, const float* __restrict__ bk,
    unsigned short* __restrict__ Qo, unsigned short* __restrict__ Ko) {
  __shared__ char lds[2 * BUFSZ];   // 128 KB

  const int tid = threadIdx.x;
  const int w = tid >> 6;
  const int l = tid & 63;
  const int lrow = l & 15, lgrp = l >> 4;
  const int wm = w >> 2, wn = w & 3;

  const int orig = blockIdx.x;          // 0..255
  const int xcd = orig & 7;
  const int slot = orig >> 3;           // 0..31
  const int nz = slot >> 2;             // 0..7
  const int mtile = (xcd * 4 + (slot & 3)) * QBM;
  const int ntile = (nz & 3) * QBN;
  const int z = nz >> 2;                // 0..1

  const unsigned short* Wz = Wbf + (long long)z * H_ * H_;

  const int srow = l >> 3;
  const int sslot = l & 7;
  auto stageOpA = [&](char* buf, int half, int k0) {
    #pragma unroll
    for (int jj = 0; jj < 2; ++jj) {
      int j = w * 2 + jj;
      int row = half * 128 + j * 8 + srow;
      int so = (sslot ^ (row & 7)) * 8;
      gld_lds16(buf + (half * 16 + j) * 1024,
                Xbf + (long long)(mtile + row) * H_ + k0 + so);
    }
  };
  auto stageOpB = [&](char* buf, int half, int k0) {
    #pragma unroll
    for (int jj = 0; jj < 2; ++jj) {
      int j = w * 2 + jj;
      int row = half * 128 + j * 8 + srow;
      int so = (sslot ^ (row & 7)) * 8;
      gld_lds16(buf + REG_B + (half * 16 + j) * 1024,
                Wz + (long long)(ntile + row) * H_ + k0 + so);
    }
  };

  auto rdA = [&](const char* buf, int ms, int fi, int ks) -> short8 {
    int r = ms * 128 + wm * 64 + fi * 16 + lrow;
    return *(const short8*)(buf + r * 128 + (((ks * 4 + lgrp) ^ (r & 7)) * 16));
  };
  auto rdB = [&](const char* buf, int ns, int fj, int ks) -> short8 {
    int r = ns * 128 + wn * 32 + fj * 16 + lrow;
    return *(const short8*)(buf + REG_B + r * 128 + (((ks * 4 + lgrp) ^ (r & 7)) * 16));
  };

  f32x4 acc[8][4];
  f32x4 zero = {0.f, 0.f, 0.f, 0.f};
  #pragma unroll
  for (int a = 0; a < 8; ++a)
    #pragma unroll
    for (int c = 0; c < 4; ++c) acc[a][c] = zero;

  short8 A[4][2], B0[2][2], B1[2][2];

  stageOpA(lds, 0, 0);
  stageOpB(lds, 0, 0);
  stageOpB(lds, 1, 0);
  stageOpA(lds, 1, 0);
  stageOpA(lds + BUFSZ, 0, QBK);
  SCHED0(); WAIT_VM(6); SCHED0();
  SBAR();

  #pragma unroll 1
  for (int t = 0; t < 15; ++t) {
    char* bc = lds + ((t & 1) ? BUFSZ : 0);
    char* bn = lds + ((t & 1) ? 0 : BUFSZ);
    const int k1 = (t + 1) * QBK;
    const int k2 = (t + 2) * QBK;
    const bool st2 = (t + 2 < 16);

    RD_A(bc, 0);
    RD_B(B0, bc, 0);
    stageOpB(bn, 0, k1);
    WAIT_LGKM0(); SCHED0();
    PRIO1(); MMQ(0, 0, A, B0); PRIO0();
    SCHED0(); WAIT_VM(6); SCHED0();
    SBAR();

    RD_B(B1, bc, 1);
    stageOpB(bn, 1, k1);
    WAIT_LGKM0(); SCHED0();
    PRIO1(); MMQ(0, 2, A, B1); PRIO0();
    SCHED0(); WAIT_VM(6); SCHED0();
    SBAR();

    RD_A(bc, 1);
    stageOpA(bn, 1, k1);
    WAIT_LGKM0(); SCHED0();
    PRIO1(); MMQ(4, 2, A, B1); PRIO0();
    SCHED0(); WAIT_VM(6); SCHED0();
    SBAR();

    if (st2) stageOpA(bc, 0, k2);
    PRIO1(); MMQ(4, 0, A, B0); PRIO0();
    SCHED0(); WAIT_VM(6); SCHED0();
    SBAR();
  }

  SCHED0(); WAIT_VM(0); SCHED0();
  SBAR();
  {
    char* bc = lds + BUFSZ;
    RD_A(bc, 0);
    RD_B(B0, bc, 0);
    WAIT_LGKM0(); SCHED0();
    PRIO1(); MMQ(0, 0, A, B0); PRIO0();
    RD_B(B1, bc, 1);
    WAIT_LGKM0(); SCHED0();
    PRIO1(); MMQ(0, 2, A, B1); PRIO0();
    RD_A(bc, 1);
    WAIT_LGKM0(); SCHED0();
    PRIO1(); MMQ(4, 2, A, B1); MMQ(4, 0, A, B0); PRIO0();
  }

  const float* bias = (z == 0) ? bq : bk;
  unsigned short* O = (z == 0) ? Qo : Ko;
  #pragma unroll
  for (int nj = 0; nj < 4; ++nj) {
    int n = ntile + (nj >> 1) * 128 + wn * 32 + (nj & 1) * 16 + lrow;
    float bv_ = bias[n];
    int h = n >> 6, d = n & 63;
    #pragma unroll
    for (int mi = 0; mi < 8; ++mi)
      #pragma unroll
      for (int r = 0; r < 4; ++r) {
        int m = mtile + (mi >> 2) * 128 + wm * 64 + (mi & 3) * 16 + lgrp * 4 + r;
        float val = acc[mi][nj][r] + bv_;
        if (z == 0) val *= 0.125f * LOG2E;
        int b = m >> 10, s = m & 1023;
        O[(((long long)(b * NH_ + h)) * S_ + s) * D_ + d] = f2bf(val);
      }
  }
}

// ---------------- kernel 2b: V GEMM (R13 verbatim) -------------------------
__global__ __launch_bounds__(512, 1) void qkv_gemm_v(
    const unsigned short* __restrict__ Xbf,
    const unsigned short* __restrict__ Wbf,
    const float* __restrict__ bv,
    unsigned short* __restrict__ Vt) {
  __shared__ char lds[3 * VBUF];   // 144 KB

  const int tid = threadIdx.x;
  const int w = tid >> 6;
  const int l = tid & 63;
  const int lrow = l & 15, lgrp = l >> 4;
  const int wm = w >> 2, wn = w & 3;

  const int orig = blockIdx.x;          // 0..255
  const int xcd = orig & 7;
  const int slot = orig >> 3;           // 0..31
  const int mtile = (xcd * 8 + (slot & 7)) * 128;   // 64 m-half-tiles
  const int ntile = (slot >> 3) * QBN;              // 4 n-tiles

  const unsigned short* Wz = Wbf + 2LL * H_ * H_;

  const int srow = l >> 3;
  const int sslot = l & 7;
  auto stageW = [&](char* buf, int half, int k0) {
    #pragma unroll
    for (int jj = 0; jj < 2; ++jj) {
      int j = w * 2 + jj;
      int row = half * 128 + j * 8 + srow;
      int so = (sslot ^ (row & 7)) * 8;
      gld_lds16(buf + (half * 16 + j) * 1024,
                Wz + (long long)(ntile + row) * H_ + k0 + so);
    }
  };
  auto stageX = [&](char* buf, int k0) {
    #pragma unroll
    for (int jj = 0; jj < 2; ++jj) {
      int j = w * 2 + jj;
      int row = j * 8 + srow;
      int so = (sslot ^ (row & 7)) * 8;
      gld_lds16(buf + 32768 + j * 1024,
                Xbf + (long long)(mtile + row) * H_ + k0 + so);
    }
  };

  auto rdA = [&](const char* buf, int ms, int fi, int ks) -> short8 {  // W
    int r = ms * 128 + wm * 64 + fi * 16 + lrow;
    return *(const short8*)(buf + r * 128 + (((ks * 4 + lgrp) ^ (r & 7)) * 16));
  };
  auto rdB = [&](const char* buf, int ns, int fj, int ks) -> short8 {  // X
    int r = wn * 32 + fj * 16 + lrow;
    (void)ns;
    return *(const short8*)(buf + 32768 + r * 128 + (((ks * 4 + lgrp) ^ (r & 7)) * 16));
  };

  f32x4 acc[8][2];
  f32x4 zero = {0.f, 0.f, 0.f, 0.f};
  #pragma unroll
  for (int a = 0; a < 8; ++a)
    #pragma unroll
    for (int c = 0; c < 2; ++c) acc[a][c] = zero;

  short8 A[4][2], B0[2][2];

  stageW(lds, 0, 0); stageW(lds, 1, 0); stageX(lds, 0);
  stageW(lds + VBUF, 0, QBK); stageW(lds + VBUF, 1, QBK); stageX(lds + VBUF, QBK);
  SCHED0(); WAIT_VM(6); SCHED0();
  SBAR();

  #pragma unroll 1
  for (int t = 0; t < 16; ++t) {
    char* bc = lds + (t % 3) * VBUF;
    char* b2 = lds + ((t + 2) % 3) * VBUF;
    const int k2 = (t + 2) * QBK;
    const bool st2 = (t + 2 < 16);

    RD_A(bc, 0);
    RD_B(B0, bc, 0);
    if (st2) { stageW(b2, 0, k2); stageW(b2, 1, k2); }
    WAIT_LGKM0(); SCHED0();
    PRIO1(); MMQ(0, 0, A, B0); PRIO0();
    SCHED0(); WAIT_VM(6); SCHED0();
    SBAR();

    RD_A(bc, 1);
    if (st2) stageX(b2, k2);
    WAIT_LGKM0(); SCHED0();
    PRIO1(); MMQ(4, 0, A, B0); PRIO0();
    SCHED0();
    if (t < 14) { WAIT_VM(6); } else { WAIT_VM(0); }
    SCHED0();
    SBAR();
  }

  #pragma unroll
  for (int mi = 0; mi < 8; ++mi)
    #pragma unroll
    for (int r = 0; r < 4; ++r) {
      int nfull = ntile + (mi >> 2) * 128 + wm * 64 + (mi & 3) * 16 + lgrp * 4 + r;
      float bv_ = bv[nfull];
      int h = nfull >> 6, d = nfull & 63;
      #pragma unroll
      for (int nj = 0; nj < 2; ++nj) {
        int mfull = mtile + wn * 32 + nj * 16 + lrow;
        float val = acc[mi][nj][r] + bv_;
        int b = mfull >> 10, s = mfull & 1023;
        Vt[(((long long)(b * NH_ + h)) * D_ + d) * S_ + s] = f2bf(val);
      }
    }
}

// ---------------- kernel 3: attention v5 — QK(t+1) ∥ softmax(t) pipeline ---
// T15 att[2]: two score sets scA/scB, 2x-unrolled loop (static indexing).
// Body t: stage K(t+2),V(t+1); QK^T(t+1)->NXT (K(t+1) resident); softmax+
// pack+PV on CUR (tile t); vmcnt(0)+SBAR. K/V each double-buffered (K(t) is
// dead when K(t+2) overwrites its slot — barrier-protected). exp2 in-place
// over CUR keeps the register delta to +32 (scB).
#define ATTN_QK(DST, KBUF)                                                 \
  {                                                                        \
    _Pragma("unroll")                                                      \
    for (int kb_ = 0; kb_ < 2; ++kb_) {                                    \
      short8 kf[4];                                                        \
      _Pragma("unroll")                                                    \
      for (int ks_ = 0; ks_ < 4; ++ks_) {                                  \
        int row_ = kb_ * 32 + l31;                                         \
        int g_ = (2 * ks_ + h) ^ (row_ & 7);                               \
        kf[ks_] = *(const short8*)((KBUF) + row_ * 128 + g_ * 16);         \
      }                                                                    \
      _Pragma("unroll")                                                    \
      for (int r_ = 0; r_ < 16; ++r_) DST[kb_][r_] = 0.f;                  \
      PRIO1();                                                             \
      _Pragma("unroll")                                                    \
      for (int ks_ = 0; ks_ < 4; ++ks_)                                    \
        DST[kb_] = __builtin_amdgcn_mfma_f32_32x32x16_bf16(                \
            kf[ks_], qf[ks_], DST[kb_], 0, 0, 0);                          \
      PRIO0();                                                             \
    }                                                                      \
  }

#define ATTN_BODY(T, CUR, NXT)                                             \
  {                                                                        \
    const int t_ = (T);                                                    \
    const bool hasN = (t_ + 1 < 16);                                       \
    if (t_ + 2 < 16) stageK(t_ + 2, lds + ((t_ & 1) << 13));               \
    if (hasN) stageV(t_ + 1, lds + 16384 + (((t_ + 1) & 1) << 13));        \
    if (hasN) { ATTN_QK(NXT, lds + (((t_ + 1) & 1) << 13)); }              \
    const int key0_ = t_ * 64;                                             \
    _Pragma("unroll")                                                      \
    for (int kb_ = 0; kb_ < 2; ++kb_)                                      \
      _Pragma("unroll")                                                    \
      for (int rg_ = 0; rg_ < 4; ++rg_) {                                  \
        f32x4 m4 = *(const f32x4*)(ldsM + (key0_ + kb_ * 32 + rg_ * 8 + 4 * h) * 4); \
        _Pragma("unroll")                                                  \
        for (int c_ = 0; c_ < 4; ++c_)                                     \
          CUR[kb_][rg_ * 4 + c_] = EXP2(CUR[kb_][rg_ * 4 + c_] + m4[c_]);  \
      }                                                                    \
    {                                                                      \
      float r16[16];                                                       \
      _Pragma("unroll")                                                    \
      for (int i_ = 0; i_ < 16; ++i_) r16[i_] = CUR[0][i_] + CUR[1][i_];   \
      _Pragma("unroll")                                                    \
      for (int i_ = 0; i_ < 8; ++i_) r16[i_] = r16[i_] + r16[i_ + 8];      \
      _Pragma("unroll")                                                    \
      for (int i_ = 0; i_ < 4; ++i_) r16[i_] = r16[i_] + r16[i_ + 4];      \
      float ps = (r16[0] + r16[1]) + (r16[2] + r16[3]);                    \
      float xs = ps, ys = ps;                                              \
      asm volatile("v_permlane32_swap_b32 %0, %1" : "+v"(xs), "+v"(ys));   \
      l_run += xs + ys;                                                    \
    }                                                                      \
    short8 pfrag[4];                                                       \
    {                                                                      \
      unsigned Wd[8][2];                                                   \
      _Pragma("unroll")                                                    \
      for (int j_ = 0; j_ < 8; ++j_) {                                     \
        asm("v_cvt_pk_bf16_f32 %0, %1, %2" : "=v"(Wd[j_][0])               \
            : "v"(CUR[j_ >> 2][(j_ & 3) * 4 + 0]), "v"(CUR[j_ >> 2][(j_ & 3) * 4 + 1])); \
        asm("v_cvt_pk_bf16_f32 %0, %1, %2" : "=v"(Wd[j_][1])               \
            : "v"(CUR[j_ >> 2][(j_ & 3) * 4 + 2]), "v"(CUR[j_ >> 2][(j_ & 3) * 4 + 3])); \
      }                                                                    \
      _Pragma("unroll")                                                    \
      for (int ks_ = 0; ks_ < 4; ++ks_) {                                  \
        unsigned x0 = Wd[2 * ks_][0], y0 = Wd[2 * ks_ + 1][0];             \
        unsigned x1 = Wd[2 * ks_][1], y1 = Wd[2 * ks_ + 1][1];             \
        asm volatile("v_permlane32_swap_b32 %0, %1" : "+v"(x0), "+v"(y0)); \
        asm volatile("v_permlane32_swap_b32 %0, %1" : "+v"(x1), "+v"(y1)); \
        union { unsigned u[4]; short8 s; } fu;                             \
        fu.u[0] = x0; fu.u[1] = x1; fu.u[2] = y0; fu.u[3] = y1;            \
        pfrag[ks_] = fu.s;                                                 \
      }                                                                    \
    }                                                                      \
    {                                                                      \
      char* vb = lds + 16384 + ((t_ & 1) << 13);                           \
      _Pragma("unroll")                                                    \
      for (int db_ = 0; db_ < 2; ++db_) {                                  \
        short8 vf[4];                                                      \
        _Pragma("unroll")                                                  \
        for (int ks_ = 0; ks_ < 4; ++ks_) {                                \
          int row_ = db_ * 32 + l31;                                       \
          int g_ = (2 * ks_ + h) ^ (row_ & 7);                             \
          vf[ks_] = *(const short8*)(vb + row_ * 128 + g_ * 16);           \
        }                                                                  \
        PRIO1();                                                           \
        _Pragma("unroll")                                                  \
        for (int ks_ = 0; ks_ < 4; ++ks_)                                  \
          acc[db_] = __builtin_amdgcn_mfma_f32_32x32x16_bf16(              \
              vf[ks_], pfrag[ks_], acc[db_], 0, 0, 0);                     \
        PRIO0();                                                           \
      }                                                                    \
    }                                                                      \
    if (hasN) { SCHED0(); WAIT_VM(0); SCHED0(); SBAR(); }                  \
  }

__global__ __launch_bounds__(256, 2) void attn_fused(
    const unsigned short* __restrict__ Qbf,
    const unsigned short* __restrict__ Kbf,
    const unsigned short* __restrict__ Vtb,
    const float* __restrict__ mask,
    float* __restrict__ out) {
  __shared__ char lds[2 * 8192 + 2 * 8192 + 4096];  // K dbuf | V dbuf | mask
  char* ldsM = lds + 32768;
  const int tid = threadIdx.x, w = tid >> 6, l = tid & 63;
  const int l31 = l & 31, h = l >> 5;

  const int lid = blockIdx.x;                 // 0..1023
  const int xcd = lid & 7, k = lid >> 3;      // all 8 q-tiles of a bh -> 1 XCD
  const int bh = xcd * 16 + (k >> 3);
  const int qt = k & 7;
  const int b = bh >> 4, hd = bh & 15;
  const int q0 = qt * 128 + w * 32;

  const unsigned short* Kg = Kbf + (long long)bh * S_ * D_;
  const unsigned short* Vg = Vtb + (long long)bh * D_ * S_;
  const float* mrow = mask + b * S_;

  auto stageK = [&](int kt, char* buf) {
    const int key0 = kt * 64;
    #pragma unroll
    for (int t = 0; t < 2; ++t) {
      int j = w * 2 + t;
      int row = j * 8 + (l >> 3);
      int so = ((l & 7) ^ (row & 7)) * 8;
      gld_lds16(buf + j * 1024, Kg + (long long)(key0 + row) * D_ + so);
    }
  };
  auto stageV = [&](int kt, char* buf) {
    const int key0 = kt * 64;
    #pragma unroll
    for (int t = 0; t < 2; ++t) {
      int j = w * 2 + t;
      int row = j * 8 + (l >> 3);
      int so = ((l & 7) ^ (row & 7)) * 8;
      gld_lds16(buf + j * 1024, Vg + (long long)row * S_ + key0 + so);
    }
  };

  // ---- prologue: qf, mask pre-transform, stage K0,V0,K1; QK(tile 0)
  short8 qf[4];
  #pragma unroll
  for (int ks = 0; ks < 4; ++ks)
    qf[ks] = *(const short8*)(Qbf + ((long long)bh * S_ + q0 + l31) * D_ + ks * 16 + 8 * h);
  {
    float4 mv = *(const float4*)(mrow + tid * 4);
    f32x4 mt;
    mt[0] = mv.x * LOG2E - 12.f;
    mt[1] = mv.y * LOG2E - 12.f;
    mt[2] = mv.z * LOG2E - 12.f;
    mt[3] = mv.w * LOG2E - 12.f;
    *(f32x4*)(ldsM + tid * 16) = mt;
  }
  stageK(0, lds);
  stageV(0, lds + 16384);
  stageK(1, lds + 8192);
  SCHED0(); WAIT_VM(0); SCHED0();
  __syncthreads();                   // mask + K0/V0/K1 published

  f32x16 acc[2];
  #pragma unroll
  for (int db = 0; db < 2; ++db)
    #pragma unroll
    for (int r = 0; r < 16; ++r) acc[db][r] = 0.f;
  float l_run = 0.f;

  f32x16 scA[2], scB[2];
  ATTN_QK(scA, lds);                 // scores for tile 0 (K0 in kbuf0)
  WAIT_LGKM0(); SCHED0();
  SBAR();                            // all waves done reading kbuf0 -> body 0 may overwrite it

  #pragma unroll 1
  for (int t = 0; t < 16; t += 2) {
    ATTN_BODY(t,     scA, scB);
    ATTN_BODY(t + 1, scB, scA);
  }

  // ---- epilogue
  {
    float inv = 1.0f / l_run;
    int q = q0 + l31;
    float* orow = out + ((long long)b * S_ + q) * H_ + hd * D_;
    #pragma unroll
    for (int db = 0; db < 2; ++db)
      #pragma unroll
      for (int rg = 0; rg < 4; ++rg) {
        f32x4 v4;
        #pragma unroll
        for (int c = 0; c < 4; ++c) v4[c] = acc[db][rg * 4 + c] * inv;
        *(f32x4*)(orow + db * 32 + rg * 8 + 4 * h) = v4;
      }
  }
}

// ---------------- launcher -------------------------------------------------
extern "C" void kernel_launch(void* const* d_in, const int* in_sizes, int n_in,
                              void* d_out, int out_size, void* d_ws, size_t ws_size,
                              hipStream_t stream) {
  const float* X    = (const float*)d_in[0];
  const float* mask = (const float*)d_in[1];
  const float* Wq   = (const float*)d_in[2];
  const float* bq   = (const float*)d_in[3];
  const float* Wk   = (const float*)d_in[4];
  const float* bk   = (const float*)d_in[5];
  const float* Wv   = (const float*)d_in[6];
  const float* bv   = (const float*)d_in[7];
  float* out = (float*)d_out;

  char* ws = (char*)d_ws;
  unsigned short* Xbf = (unsigned short*)ws;                 // 16 MB
  unsigned short* Wbf = (unsigned short*)(ws + 16777216);    //  6 MB
  unsigned short* Qb  = (unsigned short*)(ws + 23068672);    // 16 MB
  unsigned short* Kb  = (unsigned short*)(ws + 39845888);    // 16 MB
  unsigned short* Vt  = (unsigned short*)(ws + 56623104);    // 16 MB

  hipLaunchKernelGGL(cvt_f32_bf16, dim3(2048), dim3(256), 0, stream,
                     X, Wq, Wk, Wv, Xbf, Wbf);
  hipLaunchKernelGGL(qkv_gemm_qk, dim3(256), dim3(512), 0, stream,
                     Xbf, Wbf, bq, bk, Qb, Kb);
  hipLaunchKernelGGL(qkv_gemm_v, dim3(256), dim3(512), 0, stream,
                     Xbf, Wbf, bv, Vt);
  hipLaunchKernelGGL(attn_fused, dim3(1024), dim3(256), 0, stream,
                     Qb, Kb, Vt, mask, out);
}

// Round 16
// 117.061 us; speedup vs baseline: 1.0266x; 1.0266x over previous
//
#include <hip/hip_runtime.h>
#include <hip/hip_bf16.h>
#include <stdint.h>

#define B_ 8
#define S_ 1024
#define NH_ 16
#define D_ 64
#define H_ 1024
#define M_TOT (B_*S_)
#define LOG2E 1.44269504088896f

typedef __attribute__((ext_vector_type(8))) short short8;
typedef __attribute__((ext_vector_type(4))) float f32x4;
typedef __attribute__((ext_vector_type(16))) float f32x16;

#if __has_builtin(__builtin_amdgcn_exp2f)
#define EXP2(x) __builtin_amdgcn_exp2f(x)
#else
#define EXP2(x) __expf((x) * 0.69314718056f)
#endif

static __device__ __forceinline__ unsigned short f2bf(float f) {
  union { float f; unsigned u; } c; c.f = f;
  unsigned u = c.u;
  return (unsigned short)((u + 0x7fffu + ((u >> 16) & 1u)) >> 16);
}

static __device__ __forceinline__ void gld_lds16(void* lds, const void* g) {
  __builtin_amdgcn_global_load_lds((const __attribute__((address_space(1))) unsigned*)g,
                                   (__attribute__((address_space(3))) unsigned*)lds, 16, 0, 0);
}

#define WAIT_LGKM0() asm volatile("s_waitcnt lgkmcnt(0)" ::: "memory")
#define WAIT_VM(n)   asm volatile("s_waitcnt vmcnt(" #n ")" ::: "memory")
#define SBAR()       __builtin_amdgcn_s_barrier()
#define SCHED0()     __builtin_amdgcn_sched_barrier(0)
#define PRIO1()      __builtin_amdgcn_s_setprio(1)
#define PRIO0()      __builtin_amdgcn_s_setprio(0)

// ---------------- kernel 1: f32 -> bf16 conversion (X and the 3 weights) ----
__global__ void cvt_f32_bf16(const float* __restrict__ X,
                             const float* __restrict__ Wq,
                             const float* __restrict__ Wk,
                             const float* __restrict__ Wv,
                             unsigned short* __restrict__ Xbf,
                             unsigned short* __restrict__ Wbf) {
  const long long NX = (long long)M_TOT * H_;
  const long long NW = (long long)H_ * H_;
  long long t = (long long)blockIdx.x * blockDim.x + threadIdx.x;
  const long long stride = (long long)gridDim.x * blockDim.x;
  const long long total4 = (NX + 3 * NW) >> 2;
  for (; t < total4; t += stride) {
    long long e = t << 2;
    const float* src; unsigned short* dst;
    if (e < NX) { src = X + e; dst = Xbf + e; }
    else {
      long long r = e - NX;
      int w = (int)(r / NW);
      long long o = r - (long long)w * NW;
      src = (w == 0 ? Wq : (w == 1 ? Wk : Wv)) + o;
      dst = Wbf + (long long)w * NW + o;
    }
    float4 v = *(const float4*)src;
    ushort4 u;
    u.x = f2bf(v.x); u.y = f2bf(v.y); u.z = f2bf(v.z); u.w = f2bf(v.w);
    *(ushort4*)dst = u;
  }
}

// ---------------- shared GEMM macros (R9-verified) --------------------------
#define QBM 256
#define QBN 256
#define QBK 64
#define REG_B 32768
#define BUFSZ 65536
#define VBUF  49152

#define MMQ(I0, J0, AF, BF)                                               \
  _Pragma("unroll")                                                       \
  for (int a_ = 0; a_ < 4; ++a_)                                          \
    _Pragma("unroll")                                                     \
    for (int b_ = 0; b_ < 2; ++b_)                                        \
      _Pragma("unroll")                                                   \
      for (int k_ = 0; k_ < 2; ++k_)                                      \
        acc[(I0) + a_][(J0) + b_] = __builtin_amdgcn_mfma_f32_16x16x32_bf16( \
            AF[a_][k_], BF[b_][k_], acc[(I0) + a_][(J0) + b_], 0, 0, 0);

#define RD_A(BUF, MS)                                                     \
  _Pragma("unroll")                                                       \
  for (int f_ = 0; f_ < 4; ++f_)                                          \
    _Pragma("unroll")                                                     \
    for (int k_ = 0; k_ < 2; ++k_) A[f_][k_] = rdA(BUF, MS, f_, k_);

#define RD_B(DST, BUF, NS)                                                \
  _Pragma("unroll")                                                       \
  for (int f_ = 0; f_ < 2; ++f_)                                          \
    _Pragma("unroll")                                                     \
    for (int k_ = 0; k_ < 2; ++k_) DST[f_][k_] = rdB(BUF, NS, f_, k_);

// ---------------- kernel 2a: Q+K GEMM — 256 full 256^2 tiles, one round ----
__global__ __launch_bounds__(512, 1) void qkv_gemm_qk(
    const unsigned short* __restrict__ Xbf,
    const unsigned short* __restrict__ Wbf,
    const float* __restrict__ bq, const float* __restrict__ bk,
    unsigned short* __restrict__ Qo, unsigned short* __restrict__ Ko) {
  __shared__ char lds[2 * BUFSZ];   // 128 KB

  const int tid = threadIdx.x;
  const int w = tid >> 6;
  const int l = tid & 63;
  const int lrow = l & 15, lgrp = l >> 4;
  const int wm = w >> 2, wn = w & 3;

  const int orig = blockIdx.x;          // 0..255
  const int xcd = orig & 7;
  const int slot = orig >> 3;           // 0..31
  const int nz = slot >> 2;             // 0..7
  const int mtile = (xcd * 4 + (slot & 3)) * QBM;
  const int ntile = (nz & 3) * QBN;
  const int z = nz >> 2;                // 0..1

  const unsigned short* Wz = Wbf + (long long)z * H_ * H_;

  const int srow = l >> 3;
  const int sslot = l & 7;
  auto stageOpA = [&](char* buf, int half, int k0) {
    #pragma unroll
    for (int jj = 0; jj < 2; ++jj) {
      int j = w * 2 + jj;
      int row = half * 128 + j * 8 + srow;
      int so = (sslot ^ (row & 7)) * 8;
      gld_lds16(buf + (half * 16 + j) * 1024,
                Xbf + (long long)(mtile + row) * H_ + k0 + so);
    }
  };
  auto stageOpB = [&](char* buf, int half, int k0) {
    #pragma unroll
    for (int jj = 0; jj < 2; ++jj) {
      int j = w * 2 + jj;
      int row = half * 128 + j * 8 + srow;
      int so = (sslot ^ (row & 7)) * 8;
      gld_lds16(buf + REG_B + (half * 16 + j) * 1024,
                Wz + (long long)(ntile + row) * H_ + k0 + so);
    }
  };

  auto rdA = [&](const char* buf, int ms, int fi, int ks) -> short8 {
    int r = ms * 128 + wm * 64 + fi * 16 + lrow;
    return *(const short8*)(buf + r * 128 + (((ks * 4 + lgrp) ^ (r & 7)) * 16));
  };
  auto rdB = [&](const char* buf, int ns, int fj, int ks) -> short8 {
    int r = ns * 128 + wn * 32 + fj * 16 + lrow;
    return *(const short8*)(buf + REG_B + r * 128 + (((ks * 4 + lgrp) ^ (r & 7)) * 16));
  };

  f32x4 acc[8][4];
  f32x4 zero = {0.f, 0.f, 0.f, 0.f};
  #pragma unroll
  for (int a = 0; a < 8; ++a)
    #pragma unroll
    for (int c = 0; c < 4; ++c) acc[a][c] = zero;

  short8 A[4][2], B0[2][2], B1[2][2];

  stageOpA(lds, 0, 0);
  stageOpB(lds, 0, 0);
  stageOpB(lds, 1, 0);
  stageOpA(lds, 1, 0);
  stageOpA(lds + BUFSZ, 0, QBK);
  SCHED0(); WAIT_VM(6); SCHED0();
  SBAR();

  #pragma unroll 1
  for (int t = 0; t < 15; ++t) {
    char* bc = lds + ((t & 1) ? BUFSZ : 0);
    char* bn = lds + ((t & 1) ? 0 : BUFSZ);
    const int k1 = (t + 1) * QBK;
    const int k2 = (t + 2) * QBK;
    const bool st2 = (t + 2 < 16);

    RD_A(bc, 0);
    RD_B(B0, bc, 0);
    stageOpB(bn, 0, k1);
    WAIT_LGKM0(); SCHED0();
    PRIO1(); MMQ(0, 0, A, B0); PRIO0();
    SCHED0(); WAIT_VM(6); SCHED0();
    SBAR();

    RD_B(B1, bc, 1);
    stageOpB(bn, 1, k1);
    WAIT_LGKM0(); SCHED0();
    PRIO1(); MMQ(0, 2, A, B1); PRIO0();
    SCHED0(); WAIT_VM(6); SCHED0();
    SBAR();

    RD_A(bc, 1);
    stageOpA(bn, 1, k1);
    WAIT_LGKM0(); SCHED0();
    PRIO1(); MMQ(4, 2, A, B1); PRIO0();
    SCHED0(); WAIT_VM(6); SCHED0();
    SBAR();

    if (st2) stageOpA(bc, 0, k2);
    PRIO1(); MMQ(4, 0, A, B0); PRIO0();
    SCHED0(); WAIT_VM(6); SCHED0();
    SBAR();
  }

  SCHED0(); WAIT_VM(0); SCHED0();
  SBAR();
  {
    char* bc = lds + BUFSZ;
    RD_A(bc, 0);
    RD_B(B0, bc, 0);
    WAIT_LGKM0(); SCHED0();
    PRIO1(); MMQ(0, 0, A, B0); PRIO0();
    RD_B(B1, bc, 1);
    WAIT_LGKM0(); SCHED0();
    PRIO1(); MMQ(0, 2, A, B1); PRIO0();
    RD_A(bc, 1);
    WAIT_LGKM0(); SCHED0();
    PRIO1(); MMQ(4, 2, A, B1); MMQ(4, 0, A, B0); PRIO0();
  }

  const float* bias = (z == 0) ? bq : bk;
  unsigned short* O = (z == 0) ? Qo : Ko;
  #pragma unroll
  for (int nj = 0; nj < 4; ++nj) {
    int n = ntile + (nj >> 1) * 128 + wn * 32 + (nj & 1) * 16 + lrow;
    float bv_ = bias[n];
    int h = n >> 6, d = n & 63;
    #pragma unroll
    for (int mi = 0; mi < 8; ++mi)
      #pragma unroll
      for (int r = 0; r < 4; ++r) {
        int m = mtile + (mi >> 2) * 128 + wm * 64 + (mi & 3) * 16 + lgrp * 4 + r;
        float val = acc[mi][nj][r] + bv_;
        if (z == 0) val *= 0.125f * LOG2E;
        int b = m >> 10, s = m & 1023;
        O[(((long long)(b * NH_ + h)) * S_ + s) * D_ + d] = f2bf(val);
      }
  }
}

// ---------------- kernel 2b: V GEMM — 256 half-tiles (W 256 x X 128) -------
__global__ __launch_bounds__(512, 1) void qkv_gemm_v(
    const unsigned short* __restrict__ Xbf,
    const unsigned short* __restrict__ Wbf,
    const float* __restrict__ bv,
    unsigned short* __restrict__ Vt) {
  __shared__ char lds[3 * VBUF];   // 144 KB

  const int tid = threadIdx.x;
  const int w = tid >> 6;
  const int l = tid & 63;
  const int lrow = l & 15, lgrp = l >> 4;
  const int wm = w >> 2, wn = w & 3;

  const int orig = blockIdx.x;          // 0..255
  const int xcd = orig & 7;
  const int slot = orig >> 3;           // 0..31
  const int mtile = (xcd * 8 + (slot & 7)) * 128;   // 64 m-half-tiles
  const int ntile = (slot >> 3) * QBN;              // 4 n-tiles

  const unsigned short* Wz = Wbf + 2LL * H_ * H_;

  const int srow = l >> 3;
  const int sslot = l & 7;
  auto stageW = [&](char* buf, int half, int k0) {
    #pragma unroll
    for (int jj = 0; jj < 2; ++jj) {
      int j = w * 2 + jj;
      int row = half * 128 + j * 8 + srow;
      int so = (sslot ^ (row & 7)) * 8;
      gld_lds16(buf + (half * 16 + j) * 1024,
                Wz + (long long)(ntile + row) * H_ + k0 + so);
    }
  };
  auto stageX = [&](char* buf, int k0) {
    #pragma unroll
    for (int jj = 0; jj < 2; ++jj) {
      int j = w * 2 + jj;
      int row = j * 8 + srow;
      int so = (sslot ^ (row & 7)) * 8;
      gld_lds16(buf + 32768 + j * 1024,
                Xbf + (long long)(mtile + row) * H_ + k0 + so);
    }
  };

  auto rdA = [&](const char* buf, int ms, int fi, int ks) -> short8 {  // W
    int r = ms * 128 + wm * 64 + fi * 16 + lrow;
    return *(const short8*)(buf + r * 128 + (((ks * 4 + lgrp) ^ (r & 7)) * 16));
  };
  auto rdB = [&](const char* buf, int ns, int fj, int ks) -> short8 {  // X
    int r = wn * 32 + fj * 16 + lrow;
    (void)ns;
    return *(const short8*)(buf + 32768 + r * 128 + (((ks * 4 + lgrp) ^ (r & 7)) * 16));
  };

  f32x4 acc[8][2];
  f32x4 zero = {0.f, 0.f, 0.f, 0.f};
  #pragma unroll
  for (int a = 0; a < 8; ++a)
    #pragma unroll
    for (int c = 0; c < 2; ++c) acc[a][c] = zero;

  short8 A[4][2], B0[2][2];

  stageW(lds, 0, 0); stageW(lds, 1, 0); stageX(lds, 0);
  stageW(lds + VBUF, 0, QBK); stageW(lds + VBUF, 1, QBK); stageX(lds + VBUF, QBK);
  SCHED0(); WAIT_VM(6); SCHED0();
  SBAR();

  #pragma unroll 1
  for (int t = 0; t < 16; ++t) {
    char* bc = lds + (t % 3) * VBUF;
    char* b2 = lds + ((t + 2) % 3) * VBUF;
    const int k2 = (t + 2) * QBK;
    const bool st2 = (t + 2 < 16);

    RD_A(bc, 0);
    RD_B(B0, bc, 0);
    if (st2) { stageW(b2, 0, k2); stageW(b2, 1, k2); }
    WAIT_LGKM0(); SCHED0();
    PRIO1(); MMQ(0, 0, A, B0); PRIO0();
    SCHED0(); WAIT_VM(6); SCHED0();
    SBAR();

    RD_A(bc, 1);
    if (st2) stageX(b2, k2);
    WAIT_LGKM0(); SCHED0();
    PRIO1(); MMQ(4, 0, A, B0); PRIO0();
    SCHED0();
    if (t < 14) { WAIT_VM(6); } else { WAIT_VM(0); }
    SCHED0();
    SBAR();
  }

  #pragma unroll
  for (int mi = 0; mi < 8; ++mi)
    #pragma unroll
    for (int r = 0; r < 4; ++r) {
      int nfull = ntile + (mi >> 2) * 128 + wm * 64 + (mi & 3) * 16 + lgrp * 4 + r;
      float bv_ = bv[nfull];
      int h = nfull >> 6, d = nfull & 63;
      #pragma unroll
      for (int nj = 0; nj < 2; ++nj) {
        int mfull = mtile + wn * 32 + nj * 16 + lrow;
        float val = acc[mi][nj][r] + bv_;
        int b = mfull >> 10, s = mfull & 1023;
        Vt[(((long long)(b * NH_ + h)) * D_ + d) * S_ + s] = f2bf(val);
      }
    }
}

// ---------------- kernel 3: attention (R12 verbatim — permlane32_swap) -----
__global__ __launch_bounds__(256, 2) void attn_fused(
    const unsigned short* __restrict__ Qbf,
    const unsigned short* __restrict__ Kbf,
    const unsigned short* __restrict__ Vtb,
    const float* __restrict__ mask,
    float* __restrict__ out) {
  __shared__ char lds[2 * 16384 + 4096];      // K|V dbuf, then mask row
  char* ldsM = lds + 32768;
  const int tid = threadIdx.x, w = tid >> 6, l = tid & 63;
  const int l31 = l & 31, h = l >> 5;

  const int lid = blockIdx.x;                 // 0..1023
  const int xcd = lid & 7, k = lid >> 3;      // all 8 q-tiles of a bh -> 1 XCD
  const int bh = xcd * 16 + (k >> 3);
  const int qt = k & 7;
  const int b = bh >> 4, hd = bh & 15;
  const int q0 = qt * 128 + w * 32;

  const unsigned short* Kg = Kbf + (long long)bh * S_ * D_;
  const unsigned short* Vg = Vtb + (long long)bh * D_ * S_;
  const float* mrow = mask + b * S_;

  auto stageKV = [&](int kt, char* buf) {
    const int key0 = kt * 64;
    #pragma unroll
    for (int t = 0; t < 2; ++t) {
      int j = w * 2 + t;
      int row = j * 8 + (l >> 3);
      int so = ((l & 7) ^ (row & 7)) * 8;
      gld_lds16(buf + j * 1024,        Kg + (long long)(key0 + row) * D_ + so);
      gld_lds16(buf + 8192 + j * 1024, Vg + (long long)row * S_ + key0 + so);
    }
  };

  short8 qf[4];
  #pragma unroll
  for (int ks = 0; ks < 4; ++ks)
    qf[ks] = *(const short8*)(Qbf + ((long long)bh * S_ + q0 + l31) * D_ + ks * 16 + 8 * h);
  {
    float4 mv = *(const float4*)(mrow + tid * 4);
    f32x4 mt;
    mt[0] = mv.x * LOG2E - 12.f;
    mt[1] = mv.y * LOG2E - 12.f;
    mt[2] = mv.z * LOG2E - 12.f;
    mt[3] = mv.w * LOG2E - 12.f;
    *(f32x4*)(ldsM + tid * 16) = mt;
  }
  stageKV(0, lds);
  SCHED0(); WAIT_VM(0); SCHED0();
  __syncthreads();

  f32x16 acc[2];
  #pragma unroll
  for (int db = 0; db < 2; ++db)
    #pragma unroll
    for (int r = 0; r < 16; ++r) acc[db][r] = 0.f;
  float l_run = 0.f;

  #pragma unroll 1
  for (int kt = 0; kt < S_ / 64; ++kt) {
    char* ldsK = lds + (kt & 1) * 16384;
    char* ldsV = ldsK + 8192;
    const int key0 = kt * 64;
    const bool st = (kt + 1 < S_ / 64);

    if (st) stageKV(kt + 1, lds + ((kt + 1) & 1) * 16384);

    f32x16 sc[2];
    #pragma unroll
    for (int kb = 0; kb < 2; ++kb)
      #pragma unroll
      for (int r = 0; r < 16; ++r) sc[kb][r] = 0.f;

    #pragma unroll
    for (int kb = 0; kb < 2; ++kb) {
      short8 kf[4];
      #pragma unroll
      for (int ks = 0; ks < 4; ++ks) {
        int row = kb * 32 + l31;
        int g = (2 * ks + h) ^ (row & 7);
        kf[ks] = *(const short8*)(ldsK + row * 128 + g * 16);
      }
      PRIO1();
      #pragma unroll
      for (int ks = 0; ks < 4; ++ks)
        sc[kb] = __builtin_amdgcn_mfma_f32_32x32x16_bf16(
            kf[ks], qf[ks], sc[kb], 0, 0, 0);
      PRIO0();
    }

    float sv[32];
    #pragma unroll
    for (int kb = 0; kb < 2; ++kb)
      #pragma unroll
      for (int rg = 0; rg < 4; ++rg) {
        f32x4 m4 = *(const f32x4*)(ldsM + (key0 + kb * 32 + rg * 8 + 4 * h) * 4);
        #pragma unroll
        for (int c = 0; c < 4; ++c)
          sv[kb * 16 + rg * 4 + c] = EXP2(sc[kb][rg * 4 + c] + m4[c]);
      }
    {
      float r16[16];
      #pragma unroll
      for (int i = 0; i < 16; ++i) r16[i] = sv[i] + sv[i + 16];
      #pragma unroll
      for (int i = 0; i < 8; ++i) r16[i] = r16[i] + r16[i + 8];
      #pragma unroll
      for (int i = 0; i < 4; ++i) r16[i] = r16[i] + r16[i + 4];
      float ps = (r16[0] + r16[1]) + (r16[2] + r16[3]);
      float xs = ps, ys = ps;
      asm volatile("v_permlane32_swap_b32 %0, %1" : "+v"(xs), "+v"(ys));
      l_run += xs + ys;
    }

    short8 pfrag[4];
    {
      unsigned Wd[8][2];
      #pragma unroll
      for (int j = 0; j < 8; ++j) {
        int base = (j >> 2) * 16 + (j & 3) * 4;
        asm("v_cvt_pk_bf16_f32 %0, %1, %2" : "=v"(Wd[j][0]) : "v"(sv[base + 0]), "v"(sv[base + 1]));
        asm("v_cvt_pk_bf16_f32 %0, %1, %2" : "=v"(Wd[j][1]) : "v"(sv[base + 2]), "v"(sv[base + 3]));
      }
      #pragma unroll
      for (int ks = 0; ks < 4; ++ks) {
        unsigned x0 = Wd[2 * ks][0], y0 = Wd[2 * ks + 1][0];
        unsigned x1 = Wd[2 * ks][1], y1 = Wd[2 * ks + 1][1];
        asm volatile("v_permlane32_swap_b32 %0, %1" : "+v"(x0), "+v"(y0));
        asm volatile("v_permlane32_swap_b32 %0, %1" : "+v"(x1), "+v"(y1));
        union { unsigned u[4]; short8 s; } fu;
        fu.u[0] = x0;
        fu.u[1] = x1;
        fu.u[2] = y0;
        fu.u[3] = y1;
        pfrag[ks] = fu.s;
      }
    }

    #pragma unroll
    for (int db = 0; db < 2; ++db) {
      short8 vf[4];
      #pragma unroll
      for (int ks = 0; ks < 4; ++ks) {
        int row = db * 32 + l31;
        int g = (2 * ks + h) ^ (row & 7);
        vf[ks] = *(const short8*)(ldsV + row * 128 + g * 16);
      }
      PRIO1();
      #pragma unroll
      for (int ks = 0; ks < 4; ++ks)
        acc[db] = __builtin_amdgcn_mfma_f32_32x32x16_bf16(
            vf[ks], pfrag[ks], acc[db], 0, 0, 0);
      PRIO0();
    }

    if (st) { SCHED0(); WAIT_VM(0); SCHED0(); SBAR(); }
  }

  {
    float inv = 1.0f / l_run;
    int q = q0 + l31;
    float* orow = out + ((long long)b * S_ + q) * H_ + hd * D_;
    #pragma unroll
    for (int db = 0; db < 2; ++db)
      #pragma unroll
      for (int rg = 0; rg < 4; ++rg) {
        f32x4 v4;
        #pragma unroll
        for (int c = 0; c < 4; ++c) v4[c] = acc[db][rg * 4 + c] * inv;
        *(f32x4*)(orow + db * 32 + rg * 8 + 4 * h) = v4;
      }
  }
}

// ---------------- launcher -------------------------------------------------
extern "C" void kernel_launch(void* const* d_in, const int* in_sizes, int n_in,
                              void* d_out, int out_size, void* d_ws, size_t ws_size,
                              hipStream_t stream) {
  const float* X    = (const float*)d_in[0];
  const float* mask = (const float*)d_in[1];
  const float* Wq   = (const float*)d_in[2];
  const float* bq   = (const float*)d_in[3];
  const float* Wk   = (const float*)d_in[4];
  const float* bk   = (const float*)d_in[5];
  const float* Wv   = (const float*)d_in[6];
  const float* bv   = (const float*)d_in[7];
  float* out = (float*)d_out;

  char* ws = (char*)d_ws;
  unsigned short* Xbf = (unsigned short*)ws;                 // 16 MB
  unsigned short* Wbf = (unsigned short*)(ws + 16777216);    //  6 MB
  unsigned short* Qb  = (unsigned short*)(ws + 23068672);    // 16 MB
  unsigned short* Kb  = (unsigned short*)(ws + 39845888);    // 16 MB
  unsigned short* Vt  = (unsigned short*)(ws + 56623104);    // 16 MB

  hipLaunchKernelGGL(cvt_f32_bf16, dim3(2048), dim3(256), 0, stream,
                     X, Wq, Wk, Wv, Xbf, Wbf);
  hipLaunchKernelGGL(qkv_gemm_qk, dim3(256), dim3(512), 0, stream,
                     Xbf, Wbf, bq, bk, Qb, Kb);
  hipLaunchKernelGGL(qkv_gemm_v, dim3(256), dim3(512), 0, stream,
                     Xbf, Wbf, bv, Vt);
  hipLaunchKernelGGL(attn_fused, dim3(1024), dim3(256), 0, stream,
                     Qb, Kb, Vt, mask, out);
}